// Round 4
// baseline (13375.664 us; speedup 1.0000x reference)
//
#include <hip/hip_runtime.h>
#include <cmath>

// Problem dims (fixed by reference)
#define SEQ 512
#define BATCH 2048
#define DIM 64
#define HID 128
#define BT 2          // batch elements per block

// Round-4 design: VALU insts can only encode v0..v255, so per-lane register
// demand MUST be < ~230. One hidden row per lane: 128-thread blocks (2 waves),
// j = tid. Weights = 48 named float4 = 192 VGPRs (named scalars: round-1
// arrays went to scratch). BT=2 batches -> 1024 blocks = 8 waves/CU.
// Activations cross lanes via double-buffered LDS, read wave-uniform
// (broadcast, conflict-free). Two barriers per step.

#define R16(M) M(0) M(1) M(2) M(3) M(4) M(5) M(6) M(7) M(8) M(9) M(10) M(11) M(12) M(13) M(14) M(15)
#define R32(M) R16(M) M(16) M(17) M(18) M(19) M(20) M(21) M(22) M(23) M(24) M(25) M(26) M(27) M(28) M(29) M(30) M(31)

__global__ __launch_bounds__(128, 2)
void rnn_kernel(const float* __restrict__ x,
                const float* __restrict__ h0,
                const float* __restrict__ W_ih,
                const float* __restrict__ b_ih,
                const float* __restrict__ W_hh,
                const float* __restrict__ b_hh,
                float* __restrict__ out) {
    __shared__ float4 xs4[2][BT][DIM / 4];    // [buf][batch][k4] : 1 KB
    __shared__ float4 act4[2][BT][HID / 4];   // [buf][batch][k4] : 2 KB
    float* xsf  = (float*)xs4;
    float* actf = (float*)act4;

    const int tid = threadIdx.x;              // hidden index j, 0..127
    const int b0 = blockIdx.x * BT;

    // ---- per-lane weight rows into named registers (192 VGPRs) ----
    const float4* wip = (const float4*)(W_ih + tid * DIM);
#define DECL_WI(i) const float4 wi##i = wip[i];
    R16(DECL_WI)
    const float4* whp = (const float4*)(W_hh + tid * HID);
#define DECL_WH(i) const float4 wh##i = whp[i];
    R32(DECL_WH)

    const float bi = b_ih[tid];
    const float bh = b_hh[tid];

    float h0r = h0[(b0 + 0) * HID + tid];
    float h1r = h0[(b0 + 1) * HID + tid];

    // x staging: thread tid loads x[t][b0 + (tid>>6)][tid&63]; since DIM=64,
    // (tid>>6)*DIM + (tid&63) == tid. Coalesced 512B per block per step.
    const float* xbase = x + (size_t)b0 * DIM + tid;

    // prologue: stage x(0) into buf 0
    xsf[tid] = xbase[0];
    __syncthreads();

    for (int t = 0; t < SEQ; ++t) {
        const int buf = t & 1;
        const int tn = (t < SEQ - 1) ? t + 1 : t;
        const float xnext = xbase[(size_t)tn * BATCH * DIM];  // prefetch

        // ---- GEMM1: a[b] = W_ih[j,:] . x[t,b,:]  (broadcast from LDS) ----
        float aP0 = 0.f, aQ0 = 0.f, aP1 = 0.f, aQ1 = 0.f;
#define G1(i) { const float4 v0 = xs4[buf][0][i]; const float4 v1 = xs4[buf][1][i]; \
                aP0 += wi##i.x * v0.x; aP0 += wi##i.y * v0.y; \
                aQ0 += wi##i.z * v0.z; aQ0 += wi##i.w * v0.w; \
                aP1 += wi##i.x * v1.x; aP1 += wi##i.y * v1.y; \
                aQ1 += wi##i.z * v1.z; aQ1 += wi##i.w * v1.w; }
        R16(G1)

        const float w0 = (aP0 + aQ0 + bi) * h0r;
        const float w1 = (aP1 + aQ1 + bi) * h1r;

        actf[buf * (BT * HID) + 0 * HID + tid] = w0;
        actf[buf * (BT * HID) + 1 * HID + tid] = w1;
        __syncthreads();

        // ---- GEMM2: c[b] = W_hh[j,:] . wih_x[b,:] (broadcast from LDS) ----
        float cP0 = 0.f, cQ0 = 0.f, cP1 = 0.f, cQ1 = 0.f;
#define G2(i) { const float4 v0 = act4[buf][0][i]; const float4 v1 = act4[buf][1][i]; \
                cP0 += wh##i.x * v0.x; cP0 += wh##i.y * v0.y; \
                cQ0 += wh##i.z * v0.z; cQ0 += wh##i.w * v0.w; \
                cP1 += wh##i.x * v1.x; cP1 += wh##i.y * v1.y; \
                cQ1 += wh##i.z * v1.z; cQ1 += wh##i.w * v1.w; }
        R32(G2)

        // stage x(t+1) into the other buffer (reads of xs[buf] are done)
        xsf[(buf ^ 1) * (BT * DIM) + tid] = xnext;

        // ---- h update ----
        h0r = tanhf(w0 + (cP0 + cQ0 + bh) * h0r);
        h1r = tanhf(w1 + (cP1 + cQ1 + bh) * h1r);
        __syncthreads();
    }

    out[(b0 + 0) * HID + tid] = h0r;
    out[(b0 + 1) * HID + tid] = h1r;
}

extern "C" void kernel_launch(void* const* d_in, const int* in_sizes, int n_in,
                              void* d_out, int out_size, void* d_ws, size_t ws_size,
                              hipStream_t stream) {
    const float* x    = (const float*)d_in[0];
    const float* h0   = (const float*)d_in[1];
    const float* W_ih = (const float*)d_in[2];
    const float* b_ih = (const float*)d_in[3];
    const float* W_hh = (const float*)d_in[4];
    const float* b_hh = (const float*)d_in[5];
    float* out = (float*)d_out;

    dim3 grid(BATCH / BT);   // 1024 blocks
    dim3 block(128);         // 2 waves
    rnn_kernel<<<grid, block, 0, stream>>>(x, h0, W_ih, b_ih, W_hh, b_hh, out);
}

// Round 5
// 8406.041 us; speedup vs baseline: 1.5912x; 1.5912x over previous
//
#include <hip/hip_runtime.h>
#include <cmath>

// Problem dims (fixed by reference)
#define SEQ 512
#define BATCH 2048
#define DIM 64
#define HID 128
#define BT 2          // batch elements per block

// Round-5 design: identical structure to round 4 (128-thread blocks, one
// hidden row per lane, double-buffered LDS activations, broadcast reads),
// plus REGISTER PINNING. Round 4 showed the compiler rematerializes
// read-only weight loads inside the loop (VGPR=128, FETCH=28.9 GB) instead
// of keeping them resident. Empty inline-asm "+v" makes each weight value
// an opaque register-resident output, forcing true residency. Demand
// ~230 VGPR fits the 256 cap of __launch_bounds__(128,2) -> 2 waves/SIMD.

#define R16(M) M(0) M(1) M(2) M(3) M(4) M(5) M(6) M(7) M(8) M(9) M(10) M(11) M(12) M(13) M(14) M(15)
#define R32(M) R16(M) M(16) M(17) M(18) M(19) M(20) M(21) M(22) M(23) M(24) M(25) M(26) M(27) M(28) M(29) M(30) M(31)

// Pin all 4 components of a float4 into VGPRs (defeats load rematerialization)
#define PIN4(F_) asm volatile("" : "+v"(F_.x), "+v"(F_.y), "+v"(F_.z), "+v"(F_.w));
#define PIN1(F_) asm volatile("" : "+v"(F_));

__global__ __launch_bounds__(128, 2)
void rnn_kernel(const float* __restrict__ x,
                const float* __restrict__ h0,
                const float* __restrict__ W_ih,
                const float* __restrict__ b_ih,
                const float* __restrict__ W_hh,
                const float* __restrict__ b_hh,
                float* __restrict__ out) {
    __shared__ float4 xs4[2][BT][DIM / 4];    // [buf][batch][k4] : 1 KB
    __shared__ float4 act4[2][BT][HID / 4];   // [buf][batch][k4] : 2 KB
    float* xsf  = (float*)xs4;
    float* actf = (float*)act4;

    const int tid = threadIdx.x;              // hidden index j, 0..127
    const int b0 = blockIdx.x * BT;

    // ---- per-lane weight rows into registers, then PIN them ----
    const float4* wip = (const float4*)(W_ih + tid * DIM);
#define DECL_WI(i) float4 wi##i = wip[i]; PIN4(wi##i)
    R16(DECL_WI)
    const float4* whp = (const float4*)(W_hh + tid * HID);
#define DECL_WH(i) float4 wh##i = whp[i]; PIN4(wh##i)
    R32(DECL_WH)

    float bi = b_ih[tid];  PIN1(bi)
    float bh = b_hh[tid];  PIN1(bh)

    float h0r = h0[(b0 + 0) * HID + tid];
    float h1r = h0[(b0 + 1) * HID + tid];

    // x staging: thread tid loads x[t][b0 + (tid>>6)][tid&63]; since DIM=64,
    // (tid>>6)*DIM + (tid&63) == tid. Coalesced 512B per block per step.
    const float* xbase = x + (size_t)b0 * DIM + tid;

    // prologue: stage x(0) into buf 0
    xsf[tid] = xbase[0];
    __syncthreads();

    for (int t = 0; t < SEQ; ++t) {
        const int buf = t & 1;
        const int tn = (t < SEQ - 1) ? t + 1 : t;
        const float xnext = xbase[(size_t)tn * BATCH * DIM];  // prefetch

        // ---- GEMM1: a[b] = W_ih[j,:] . x[t,b,:]  (broadcast from LDS) ----
        float aP0 = 0.f, aQ0 = 0.f, aP1 = 0.f, aQ1 = 0.f;
#define G1(i) { const float4 v0 = xs4[buf][0][i]; const float4 v1 = xs4[buf][1][i]; \
                aP0 += wi##i.x * v0.x; aP0 += wi##i.y * v0.y; \
                aQ0 += wi##i.z * v0.z; aQ0 += wi##i.w * v0.w; \
                aP1 += wi##i.x * v1.x; aP1 += wi##i.y * v1.y; \
                aQ1 += wi##i.z * v1.z; aQ1 += wi##i.w * v1.w; }
        R16(G1)

        const float w0 = (aP0 + aQ0 + bi) * h0r;
        const float w1 = (aP1 + aQ1 + bi) * h1r;

        actf[buf * (BT * HID) + 0 * HID + tid] = w0;
        actf[buf * (BT * HID) + 1 * HID + tid] = w1;
        __syncthreads();

        // ---- GEMM2: c[b] = W_hh[j,:] . wih_x[b,:] (broadcast from LDS) ----
        float cP0 = 0.f, cQ0 = 0.f, cP1 = 0.f, cQ1 = 0.f;
#define G2(i) { const float4 v0 = act4[buf][0][i]; const float4 v1 = act4[buf][1][i]; \
                cP0 += wh##i.x * v0.x; cP0 += wh##i.y * v0.y; \
                cQ0 += wh##i.z * v0.z; cQ0 += wh##i.w * v0.w; \
                cP1 += wh##i.x * v1.x; cP1 += wh##i.y * v1.y; \
                cQ1 += wh##i.z * v1.z; cQ1 += wh##i.w * v1.w; }
        R32(G2)

        // stage x(t+1) into the other buffer (reads of xs[buf] done by all
        // waves: they passed this step's first barrier)
        xsf[(buf ^ 1) * (BT * DIM) + tid] = xnext;

        // ---- h update ----
        h0r = tanhf(w0 + (cP0 + cQ0 + bh) * h0r);
        h1r = tanhf(w1 + (cP1 + cQ1 + bh) * h1r);
        __syncthreads();
    }

    out[(b0 + 0) * HID + tid] = h0r;
    out[(b0 + 1) * HID + tid] = h1r;
}

extern "C" void kernel_launch(void* const* d_in, const int* in_sizes, int n_in,
                              void* d_out, int out_size, void* d_ws, size_t ws_size,
                              hipStream_t stream) {
    const float* x    = (const float*)d_in[0];
    const float* h0   = (const float*)d_in[1];
    const float* W_ih = (const float*)d_in[2];
    const float* b_ih = (const float*)d_in[3];
    const float* W_hh = (const float*)d_in[4];
    const float* b_hh = (const float*)d_in[5];
    float* out = (float*)d_out;

    dim3 grid(BATCH / BT);   // 1024 blocks
    dim3 block(128);         // 2 waves
    rnn_kernel<<<grid, block, 0, stream>>>(x, h0, W_ih, b_ih, W_hh, b_hh, out);
}

// Round 6
// 3837.486 us; speedup vs baseline: 3.4855x; 2.1905x over previous
//
#include <hip/hip_runtime.h>
#include <cmath>

// Problem dims (fixed by reference)
#define SEQ 512
#define BATCH 2048
#define DIM 64
#define HID 128
#define BT 2          // batch elements per block

// Round-6 design: round-5 structure + __launch_bounds__(128, 1).
// Evidence trail: (64,1) -> 256 VGPRs (r3); (128,2) -> hard 128-VGPR budget,
// pinned weights spilled to scratch, 23 GB/launch of HBM spill reloads (r5).
// min-waves=1 unlocks the full 256 arch-VGPR cap; demand ~230 fits, actual
// usage still allows 2 waves/SIMD, and grid (1024 blocks = 8 waves/CU) fills
// exactly that. Weights pinned via empty asm (defeats remat, r4 lesson).

#define R16(M) M(0) M(1) M(2) M(3) M(4) M(5) M(6) M(7) M(8) M(9) M(10) M(11) M(12) M(13) M(14) M(15)
#define R32(M) R16(M) M(16) M(17) M(18) M(19) M(20) M(21) M(22) M(23) M(24) M(25) M(26) M(27) M(28) M(29) M(30) M(31)

// Pin all 4 components of a float4 into VGPRs (defeats load rematerialization)
#define PIN4(F_) asm volatile("" : "+v"(F_.x), "+v"(F_.y), "+v"(F_.z), "+v"(F_.w));
#define PIN1(F_) asm volatile("" : "+v"(F_));

__global__ __launch_bounds__(128, 1)
void rnn_kernel(const float* __restrict__ x,
                const float* __restrict__ h0,
                const float* __restrict__ W_ih,
                const float* __restrict__ b_ih,
                const float* __restrict__ W_hh,
                const float* __restrict__ b_hh,
                float* __restrict__ out) {
    __shared__ float4 xs4[2][BT][DIM / 4];    // [buf][batch][k4] : 1 KB
    __shared__ float4 act4[2][BT][HID / 4];   // [buf][batch][k4] : 2 KB
    float* xsf  = (float*)xs4;
    float* actf = (float*)act4;

    const int tid = threadIdx.x;              // hidden index j, 0..127
    const int b0 = blockIdx.x * BT;

    // ---- per-lane weight rows into registers, then PIN them ----
    const float4* wip = (const float4*)(W_ih + tid * DIM);
#define DECL_WI(i) float4 wi##i = wip[i]; PIN4(wi##i)
    R16(DECL_WI)
    const float4* whp = (const float4*)(W_hh + tid * HID);
#define DECL_WH(i) float4 wh##i = whp[i]; PIN4(wh##i)
    R32(DECL_WH)

    float bi = b_ih[tid];  PIN1(bi)
    float bh = b_hh[tid];  PIN1(bh)

    float h0r = h0[(b0 + 0) * HID + tid];
    float h1r = h0[(b0 + 1) * HID + tid];

    // x staging: thread tid loads x[t][b0 + (tid>>6)][tid&63]; since DIM=64,
    // (tid>>6)*DIM + (tid&63) == tid. Coalesced 512B per block per step.
    const float* xbase = x + (size_t)b0 * DIM + tid;

    // prologue: stage x(0) into buf 0
    xsf[tid] = xbase[0];
    __syncthreads();

    for (int t = 0; t < SEQ; ++t) {
        const int buf = t & 1;
        const int tn = (t < SEQ - 1) ? t + 1 : t;
        const float xnext = xbase[(size_t)tn * BATCH * DIM];  // prefetch

        // ---- GEMM1: a[b] = W_ih[j,:] . x[t,b,:]  (broadcast from LDS) ----
        float aP0 = 0.f, aQ0 = 0.f, aP1 = 0.f, aQ1 = 0.f;
#define G1(i) { const float4 v0 = xs4[buf][0][i]; const float4 v1 = xs4[buf][1][i]; \
                aP0 += wi##i.x * v0.x; aP0 += wi##i.y * v0.y; \
                aQ0 += wi##i.z * v0.z; aQ0 += wi##i.w * v0.w; \
                aP1 += wi##i.x * v1.x; aP1 += wi##i.y * v1.y; \
                aQ1 += wi##i.z * v1.z; aQ1 += wi##i.w * v1.w; }
        R16(G1)

        const float w0 = (aP0 + aQ0 + bi) * h0r;
        const float w1 = (aP1 + aQ1 + bi) * h1r;

        actf[buf * (BT * HID) + 0 * HID + tid] = w0;
        actf[buf * (BT * HID) + 1 * HID + tid] = w1;
        __syncthreads();

        // ---- GEMM2: c[b] = W_hh[j,:] . wih_x[b,:] (broadcast from LDS) ----
        float cP0 = 0.f, cQ0 = 0.f, cP1 = 0.f, cQ1 = 0.f;
#define G2(i) { const float4 v0 = act4[buf][0][i]; const float4 v1 = act4[buf][1][i]; \
                cP0 += wh##i.x * v0.x; cP0 += wh##i.y * v0.y; \
                cQ0 += wh##i.z * v0.z; cQ0 += wh##i.w * v0.w; \
                cP1 += wh##i.x * v1.x; cP1 += wh##i.y * v1.y; \
                cQ1 += wh##i.z * v1.z; cQ1 += wh##i.w * v1.w; }
        R32(G2)

        // stage x(t+1) into the other buffer (reads of xs[buf] done by all
        // waves: they passed this step's first barrier)
        xsf[(buf ^ 1) * (BT * DIM) + tid] = xnext;

        // ---- h update ----
        h0r = tanhf(w0 + (cP0 + cQ0 + bh) * h0r);
        h1r = tanhf(w1 + (cP1 + cQ1 + bh) * h1r);
        __syncthreads();
    }

    out[(b0 + 0) * HID + tid] = h0r;
    out[(b0 + 1) * HID + tid] = h1r;
}

extern "C" void kernel_launch(void* const* d_in, const int* in_sizes, int n_in,
                              void* d_out, int out_size, void* d_ws, size_t ws_size,
                              hipStream_t stream) {
    const float* x    = (const float*)d_in[0];
    const float* h0   = (const float*)d_in[1];
    const float* W_ih = (const float*)d_in[2];
    const float* b_ih = (const float*)d_in[3];
    const float* W_hh = (const float*)d_in[4];
    const float* b_hh = (const float*)d_in[5];
    float* out = (float*)d_out;

    dim3 grid(BATCH / BT);   // 1024 blocks
    dim3 block(128);         // 2 waves
    rnn_kernel<<<grid, block, 0, stream>>>(x, h0, W_ih, b_ih, W_hh, b_hh, out);
}

// Round 7
// 2288.230 us; speedup vs baseline: 5.8454x; 1.6771x over previous
//
#include <hip/hip_runtime.h>
#include <cmath>

#define SEQ 512
#define BATCH 2048
#define DIM 64
#define HID 128
#define SB (BATCH * DIM)   // x stride per timestep

// Round-7: kill the LDS pipe pressure + barrier vmcnt drain of r6.
//  - GEMM1: x in per-lane VGPRs (prefetched), k-broadcast via v_readlane (VALU).
//  - GEMM2: own 64 k's via readlane of in-wave wihx; partner 64 k's via 16
//    uniform ds_read_b128 per batch. W_hh stored own-half-first per wave.
//  - ONE barrier per iter, lgkmcnt-only drain (inline asm) so the x global
//    prefetch stays in flight across it. act tile double-buffered (WAR-safe).
// LDS instrs/wave-iter: 99 -> 34. Weights pinned in regs (r4/r5/r6 lessons):
// named scalars + empty-asm pin + __launch_bounds__(128,1) for the 256 cap.

#define R16(M) M(0) M(1) M(2) M(3) M(4) M(5) M(6) M(7) M(8) M(9) M(10) M(11) M(12) M(13) M(14) M(15)

#define PIN4(F_) asm volatile("" : "+v"(F_.x), "+v"(F_.y), "+v"(F_.z), "+v"(F_.w));
#define PIN1(F_) asm volatile("" : "+v"(F_));

__device__ __forceinline__ float RL(float v, int l) {
    return __int_as_float(__builtin_amdgcn_readlane(__float_as_int(v), l));
}

__global__ __launch_bounds__(128, 1)
void rnn_kernel(const float* __restrict__ x,
                const float* __restrict__ h0,
                const float* __restrict__ W_ih,
                const float* __restrict__ b_ih,
                const float* __restrict__ W_hh,
                const float* __restrict__ b_hh,
                float* __restrict__ out) {
    __shared__ float4 act4[2][2][HID / 4];   // [buf][batch][k4] : 2 KB
    float* actf = (float*)act4;

    const int tid = threadIdx.x;      // hidden index j = tid
    const int b0 = blockIdx.x * 2;
    const int lane = tid & 63;
    const int own_base = tid & 64;    // my wave's k-range start (0 or 64)
    const int own4 = own_base >> 2;   // float4 chunk offset (0 or 16)

    // ---- W_ih row (natural order) ----
    const float4* wip = (const float4*)(W_ih + tid * DIM);
#define DECL_WI(i) float4 wi##i = wip[i]; PIN4(wi##i)
    R16(DECL_WI)

    // ---- W_hh row, permuted: own-half chunks first, partner-half second ----
    const float4* whp = (const float4*)(W_hh + tid * HID);
#define DECL_WHN(i) float4 whn##i = whp[own4 + i]; PIN4(whn##i)
    R16(DECL_WHN)
#define DECL_WHO(i) float4 who##i = whp[(own4 ^ 16) + i]; PIN4(who##i)
    R16(DECL_WHO)

    float bi = b_ih[tid];  PIN1(bi)
    float bh = b_hh[tid];  PIN1(bh)

    float h0r = h0[(b0 + 0) * HID + tid];
    float h1r = h0[(b0 + 1) * HID + tid];

    // per-lane x staging: lane L holds x[t][b][L] for both batches
    const float* xp0 = x + (size_t)(b0 + 0) * DIM + lane;
    const float* xp1 = x + (size_t)(b0 + 1) * DIM + lane;
    float xc0 = xp0[0], xc1 = xp1[0];           // x(0)
    float xn0 = xp0[SB], xn1 = xp1[SB];         // x(1) in flight
    const float* xf0 = xp0 + 2 * (size_t)SB;    // next prefetch addr: x(2)
    const float* xf1 = xp1 + 2 * (size_t)SB;

    for (int t = 0; t < SEQ; ++t) {
        const int buf = t & 1;

        // ---- GEMM1: a[b] = W_ih[j,:] . x[t,b,:] via readlane broadcast ----
        float aP0 = 0.f, aQ0 = 0.f, aP1 = 0.f, aQ1 = 0.f;
#define G1(c) { float s_; \
        s_ = RL(xc0, 4*(c)+0); aP0 += wi##c.x * s_; \
        s_ = RL(xc1, 4*(c)+0); aP1 += wi##c.x * s_; \
        s_ = RL(xc0, 4*(c)+1); aP0 += wi##c.y * s_; \
        s_ = RL(xc1, 4*(c)+1); aP1 += wi##c.y * s_; \
        s_ = RL(xc0, 4*(c)+2); aQ0 += wi##c.z * s_; \
        s_ = RL(xc1, 4*(c)+2); aQ1 += wi##c.z * s_; \
        s_ = RL(xc0, 4*(c)+3); aQ0 += wi##c.w * s_; \
        s_ = RL(xc1, 4*(c)+3); aQ1 += wi##c.w * s_; }
        R16(G1)

        // rotate x prefetch (xn consumed next iter; new load window = 1 iter)
        xc0 = xn0; xc1 = xn1;
        xn0 = *xf0; xn1 = *xf1;
        const size_t bump = (t < SEQ - 3) ? (size_t)SB : 0;
        xf0 += bump; xf1 += bump;

        const float wihx0 = (aP0 + aQ0 + bi) * h0r;
        const float wihx1 = (aP1 + aQ1 + bi) * h1r;

        // publish wihx for the partner wave
        actf[buf * 256 + 0 * HID + tid] = wihx0;
        actf[buf * 256 + 1 * HID + tid] = wihx1;
        // LDS-only drain + barrier: x prefetch stays in flight (no vmcnt!)
        asm volatile("s_waitcnt lgkmcnt(0)\n\ts_barrier" ::: "memory");

        // ---- GEMM2 own half: k in [own_base, own_base+64), readlane ----
        float oP0 = 0.f, oQ0 = 0.f, oP1 = 0.f, oQ1 = 0.f;
#define G2O(c) { float s_; \
        s_ = RL(wihx0, 4*(c)+0); oP0 += whn##c.x * s_; \
        s_ = RL(wihx1, 4*(c)+0); oP1 += whn##c.x * s_; \
        s_ = RL(wihx0, 4*(c)+1); oP0 += whn##c.y * s_; \
        s_ = RL(wihx1, 4*(c)+1); oP1 += whn##c.y * s_; \
        s_ = RL(wihx0, 4*(c)+2); oQ0 += whn##c.z * s_; \
        s_ = RL(wihx1, 4*(c)+2); oQ1 += whn##c.z * s_; \
        s_ = RL(wihx0, 4*(c)+3); oQ0 += whn##c.w * s_; \
        s_ = RL(wihx1, 4*(c)+3); oQ1 += whn##c.w * s_; }
        R16(G2O)

        // ---- GEMM2 partner half: 16 uniform b128 reads per batch ----
        float pP0 = 0.f, pQ0 = 0.f, pP1 = 0.f, pQ1 = 0.f;
        const float4* pa0 = (const float4*)&actf[buf * 256 + 0 * HID + (own_base ^ 64)];
        const float4* pa1 = (const float4*)&actf[buf * 256 + 1 * HID + (own_base ^ 64)];
#define G2P(c) { const float4 v0 = pa0[c]; const float4 v1 = pa1[c]; \
        pP0 += who##c.x * v0.x; pP0 += who##c.y * v0.y; \
        pQ0 += who##c.z * v0.z; pQ0 += who##c.w * v0.w; \
        pP1 += who##c.x * v1.x; pP1 += who##c.y * v1.y; \
        pQ1 += who##c.z * v1.z; pQ1 += who##c.w * v1.w; }
        R16(G2P)

        // combine halves (2-operand adds commute -> wave-symmetric exact)
        const float c0 = (oP0 + pP0) + (oQ0 + pQ0);
        const float c1 = (oP1 + pP1) + (oQ1 + pQ1);

        h0r = tanhf(wihx0 + (c0 + bh) * h0r);
        h1r = tanhf(wihx1 + (c1 + bh) * h1r);
        // no trailing barrier: act is double-buffered; a wave can only reach
        // its t+2 write after passing barrier t+1, which is after all waves
        // finished their t reads.
    }

    out[(b0 + 0) * HID + tid] = h0r;
    out[(b0 + 1) * HID + tid] = h1r;
}

extern "C" void kernel_launch(void* const* d_in, const int* in_sizes, int n_in,
                              void* d_out, int out_size, void* d_ws, size_t ws_size,
                              hipStream_t stream) {
    const float* x    = (const float*)d_in[0];
    const float* h0   = (const float*)d_in[1];
    const float* W_ih = (const float*)d_in[2];
    const float* b_ih = (const float*)d_in[3];
    const float* W_hh = (const float*)d_in[4];
    const float* b_hh = (const float*)d_in[5];
    float* out = (float*)d_out;

    dim3 grid(BATCH / 2);   // 1024 blocks, BT=2
    dim3 block(128);        // 2 waves; wave w owns j in [w*64, w*64+64)
    rnn_kernel<<<grid, block, 0, stream>>>(x, h0, W_ih, b_ih, W_hh, b_hh, out);
}

// Round 8
// 1659.429 us; speedup vs baseline: 8.0604x; 1.3789x over previous
//
#include <hip/hip_runtime.h>
#include <cmath>

#define SEQ 512
#define BATCH 2048
#define DIM 64
#define HID 128
#define SB (BATCH * DIM)   // x stride per timestep (floats)

// Round-8: BT=1 (2048 blocks x 128 thr). r7 counters showed VGPR=140 with
// 192 pinned weights -> ~60-90 weights lived in AGPRs, adding v_accvgpr_read
// VALU traffic; and per-batch VALU was ~400. BT=1 cuts per-batch VALU to
// ~286 (GEMM1: 64 RL + 64 FMA; GEMM2 own-half: 64 RL + 64 FMA; partner-half:
// 16 uniform ds_read_b128 + 64 FMA) and drops register demand to ~210 so
// everything fits in arch VGPRs. 3-deep x prefetch (t,t+1,t+2 in regs) gives
// the only global load a ~2-iteration window. One lgkmcnt-only barrier/iter
// (x prefetch stays in flight across it); act tile double-buffered (WAR-safe
// by the barrier-ordering argument). Weights pinned (r4-r6 lessons) with
// __launch_bounds__(128,1) for the 256-reg cap.

#define R16(M) M(0) M(1) M(2) M(3) M(4) M(5) M(6) M(7) M(8) M(9) M(10) M(11) M(12) M(13) M(14) M(15)

#define PIN4(F_) asm volatile("" : "+v"(F_.x), "+v"(F_.y), "+v"(F_.z), "+v"(F_.w));
#define PIN1(F_) asm volatile("" : "+v"(F_));

__device__ __forceinline__ float RL(float v, int l) {
    return __int_as_float(__builtin_amdgcn_readlane(__float_as_int(v), l));
}

__global__ __launch_bounds__(128, 1)
void rnn_kernel(const float* __restrict__ x,
                const float* __restrict__ h0,
                const float* __restrict__ W_ih,
                const float* __restrict__ b_ih,
                const float* __restrict__ W_hh,
                const float* __restrict__ b_hh,
                float* __restrict__ out) {
    __shared__ float actf[2][HID];    // double-buffered wihx tile, 1 KB

    const int tid = threadIdx.x;      // hidden index j = tid
    const int b = blockIdx.x;         // batch element
    const int lane = tid & 63;
    const int own_base = tid & 64;    // my wave's k-range start (0 or 64)
    const int own4 = own_base >> 2;   // float4 chunk offset (0 or 16)

    // ---- W_ih row (k = 0..63) ----
    const float4* wip = (const float4*)(W_ih + tid * DIM);
#define DECL_WI(i) float4 wi##i = wip[i]; PIN4(wi##i)
    R16(DECL_WI)

    // ---- W_hh row, own-half chunks then partner-half chunks ----
    const float4* whp = (const float4*)(W_hh + tid * HID);
#define DECL_WHN(i) float4 whn##i = whp[own4 + i]; PIN4(whn##i)
    R16(DECL_WHN)
#define DECL_WHO(i) float4 who##i = whp[(own4 ^ 16) + i]; PIN4(who##i)
    R16(DECL_WHO)

    float bi = b_ih[tid];  PIN1(bi)
    float bh = b_hh[tid];  PIN1(bh)

    float h = h0[b * HID + tid];

    // per-lane x staging: lane L holds x[t][b][L]; both waves load the same
    // 64 floats (second wave hits L1). 3-deep rotation: xc=t, xn=t+1, xm=t+2.
    const float* xp = x + (size_t)b * DIM + lane;
    float xc = xp[0];
    float xn = xp[(size_t)SB];
    float xm = xp[2 * (size_t)SB];
    const float* xf = xp + 3 * (size_t)SB;

    for (int t = 0; t < SEQ; ++t) {
        const int buf = t & 1;

        // ---- GEMM1: a = W_ih[j,:] . x[t,b,:] via readlane broadcast ----
        float aP = 0.f, aQ = 0.f;
#define G1(c) { float s_; \
        s_ = RL(xc, 4*(c)+0); aP += wi##c.x * s_; \
        s_ = RL(xc, 4*(c)+1); aP += wi##c.y * s_; \
        s_ = RL(xc, 4*(c)+2); aQ += wi##c.z * s_; \
        s_ = RL(xc, 4*(c)+3); aQ += wi##c.w * s_; }
        R16(G1)

        // rotate the x prefetch pipeline (xm's load has ~2 iters to land)
        xc = xn; xn = xm;
        xm = *xf;
        xf += (t < SEQ - 4) ? (size_t)SB : 0;

        const float wihx = (aP + aQ + bi) * h;

        // publish wihx for the partner wave
        actf[buf][tid] = wihx;
        // LDS-only drain + barrier: x prefetch stays in flight (no vmcnt)
        asm volatile("s_waitcnt lgkmcnt(0)\n\ts_barrier" ::: "memory");

        // ---- GEMM2 own half: k in [own_base, own_base+64) via readlane ----
        float oP = 0.f, oQ = 0.f;
#define G2O(c) { float s_; \
        s_ = RL(wihx, 4*(c)+0); oP += whn##c.x * s_; \
        s_ = RL(wihx, 4*(c)+1); oP += whn##c.y * s_; \
        s_ = RL(wihx, 4*(c)+2); oQ += whn##c.z * s_; \
        s_ = RL(wihx, 4*(c)+3); oQ += whn##c.w * s_; }
        R16(G2O)

        // ---- GEMM2 partner half: 16 uniform b128 reads (LDS broadcast) ----
        float pP = 0.f, pQ = 0.f;
        const float4* pa = (const float4*)&actf[buf][own_base ^ 64];
#define G2P(c) { const float4 v_ = pa[c]; \
        pP += who##c.x * v_.x; pP += who##c.y * v_.y; \
        pQ += who##c.z * v_.z; pQ += who##c.w * v_.w; }
        R16(G2P)

        // combine halves (same order as r7 -> same bits)
        const float cc = (oP + pP) + (oQ + pQ);
        h = tanhf(wihx + (cc + bh) * h);
        // no trailing barrier: act double-buffered; a wave reaches its t+2
        // write only after barrier t+1, which is after all t reads.
    }

    out[b * HID + tid] = h;
}

extern "C" void kernel_launch(void* const* d_in, const int* in_sizes, int n_in,
                              void* d_out, int out_size, void* d_ws, size_t ws_size,
                              hipStream_t stream) {
    const float* x    = (const float*)d_in[0];
    const float* h0   = (const float*)d_in[1];
    const float* W_ih = (const float*)d_in[2];
    const float* b_ih = (const float*)d_in[3];
    const float* W_hh = (const float*)d_in[4];
    const float* b_hh = (const float*)d_in[5];
    float* out = (float*)d_out;

    dim3 grid(BATCH);       // 2048 blocks, one batch element each
    dim3 block(128);        // 2 waves; wave w owns j in [w*64, w*64+64)
    rnn_kernel<<<grid, block, 0, stream>>>(x, h0, W_ih, b_ih, W_hh, b_hh, out);
}